// Round 7
// baseline (1070.565 us; speedup 1.0000x reference)
//
#include <hip/hip_runtime.h>

#define SEQ 577
#define CDIM 768
#define NHEADS 12
#define DHEAD 64
#define QKV_STRIDE 2304
#define GHID_ 512
#define HGRID_ 24
#define HWP 576
#define NTOK 9232   // 16*577

// ---------------- sentinel fill (ws too small): out = 16.0f ----------------
__global__ __launch_bounds__(256)
void fill_sentinel_kernel(float* __restrict__ out, int n)
{
    int i = blockIdx.x * 256 + threadIdx.x;
    if (i < n) out[i] = 16.0f;   // absmax ~16, unmistakable
}

// ---------------- GEMM: C(M,N) = A(M,K) @ B(K,N) + bias ----------------
// A has row stride lda (>= K). 128x128 tile, BK=16, 256 threads, 8x8/thread.
// PROJ epilogue: adds structv to token-0 rows and writes FP32 output.
template<bool PROJ>
__global__ __launch_bounds__(256)
void gemm_kernel(const float* __restrict__ A, const float* __restrict__ B,
                 const float* __restrict__ bias, float* __restrict__ C,
                 const float* __restrict__ structv,
                 int M, int N, int K, int lda)
{
    __shared__ float As[16][132];   // A transposed: As[k][m]
    __shared__ float Bs[16][132];
    const int tid = threadIdx.x;
    const int tm = tid >> 4;
    const int tn = tid & 15;
    const int m0 = blockIdx.y * 128;
    const int n0 = blockIdx.x * 128;

    float acc[8][8];
    #pragma unroll
    for (int i = 0; i < 8; ++i)
        #pragma unroll
        for (int j = 0; j < 8; ++j) acc[i][j] = 0.f;

    const int ar = tid >> 2;            // 0..63
    const int ac = (tid & 3) << 2;      // 0,4,8,12
    const int br = tid >> 5;            // 0..7
    const int bc = (tid & 31) << 2;     // 0..124

    for (int k0 = 0; k0 < K; k0 += 16) {
        #pragma unroll
        for (int half = 0; half < 2; ++half) {
            int r = ar + half * 64;
            int grow = m0 + r;
            float4 v = make_float4(0.f, 0.f, 0.f, 0.f);
            if (grow < M) v = *(const float4*)&A[(size_t)grow * lda + k0 + ac];
            As[ac + 0][r] = v.x; As[ac + 1][r] = v.y;
            As[ac + 2][r] = v.z; As[ac + 3][r] = v.w;
        }
        #pragma unroll
        for (int half = 0; half < 2; ++half) {
            int r = br + half * 8;
            *(float4*)&Bs[r][bc] = *(const float4*)&B[(size_t)(k0 + r) * N + n0 + bc];
        }
        __syncthreads();
        #pragma unroll
        for (int kk = 0; kk < 16; ++kk) {
            float a[8], bb[8];
            *(float4*)&a[0]  = *(const float4*)&As[kk][tm * 8];
            *(float4*)&a[4]  = *(const float4*)&As[kk][tm * 8 + 4];
            *(float4*)&bb[0] = *(const float4*)&Bs[kk][tn * 4];
            *(float4*)&bb[4] = *(const float4*)&Bs[kk][64 + tn * 4];
            #pragma unroll
            for (int i = 0; i < 8; ++i)
                #pragma unroll
                for (int j = 0; j < 8; ++j)
                    acc[i][j] = fmaf(a[i], bb[j], acc[i][j]);
        }
        __syncthreads();
    }

    #pragma unroll
    for (int i = 0; i < 8; ++i) {
        int grow = m0 + tm * 8 + i;
        if (grow >= M) continue;
        #pragma unroll
        for (int jq = 0; jq < 2; ++jq) {
            int col = n0 + jq * 64 + tn * 4;
            float4 bv = *(const float4*)&bias[col];
            float vals[4];
            #pragma unroll
            for (int jj = 0; jj < 4; ++jj) vals[jj] = acc[i][jq * 4 + jj];
            vals[0] += bv.x; vals[1] += bv.y; vals[2] += bv.z; vals[3] += bv.w;
            if (PROJ && (grow % SEQ == 0)) {
                int bidx = grow / SEQ;
                #pragma unroll
                for (int jj = 0; jj < 4; ++jj)
                    vals[jj] += structv[(size_t)bidx * CDIM + col + jj];
            }
            float4 o; o.x = vals[0]; o.y = vals[1]; o.z = vals[2]; o.w = vals[3];
            *(float4*)&C[(size_t)grow * N + col] = o;
        }
    }
}

// ---------------- Flash attention; y written IN PLACE over the q-plane ----------------
// Safe: each block reads its own Q into LDS in the prologue, different heads
// write disjoint 64-col slices, K/V planes never written. row0 runs BEFORE this.
__global__ __launch_bounds__(256)
void attn_kernel(float* qkv)
{
    __shared__ float Qt[DHEAD][68];   // Q transposed [d][m], pre-scaled
    __shared__ float Kt[DHEAD][68];   // K transposed [d][j]
    __shared__ float Vs[64][68];      // V row-major [j][d]
    __shared__ float Pt[64][68];      // P transposed [j][m]
    const int tid = threadIdx.x;
    const int tm = tid >> 4, tn = tid & 15;
    const int qt = blockIdx.x, h = blockIdx.y, b = blockIdx.z;
    const int q0 = qt * 64;

    {
        int r = tid >> 2;
        int c0 = (tid & 3) << 4;
        int n = q0 + r; if (n > SEQ - 1) n = SEQ - 1;
        const float* p = qkv + (size_t)(b * SEQ + n) * QKV_STRIDE + h * DHEAD + c0;
        #pragma unroll
        for (int u = 0; u < 16; u += 4) {
            float4 v = *(const float4*)&p[u];
            Qt[c0 + u + 0][r] = v.x * 0.125f;
            Qt[c0 + u + 1][r] = v.y * 0.125f;
            Qt[c0 + u + 2][r] = v.z * 0.125f;
            Qt[c0 + u + 3][r] = v.w * 0.125f;
        }
    }

    float m_run[4], l_run[4], acc[4][4];
    #pragma unroll
    for (int i = 0; i < 4; ++i) {
        m_run[i] = -1e30f; l_run[i] = 0.f;
        #pragma unroll
        for (int j = 0; j < 4; ++j) acc[i][j] = 0.f;
    }

    for (int kt = 0; kt < 10; ++kt) {
        const int j0 = kt * 64;
        __syncthreads();   // previous PV done (and Q visible on first iter)
        {
            int r = tid >> 2;
            int c0 = (tid & 3) << 4;
            int n = j0 + r; if (n > SEQ - 1) n = SEQ - 1;
            const float* kp = qkv + (size_t)(b * SEQ + n) * QKV_STRIDE + CDIM + h * DHEAD + c0;
            const float* vp = kp + CDIM;
            #pragma unroll
            for (int u = 0; u < 16; u += 4) {
                float4 v = *(const float4*)&kp[u];
                Kt[c0 + u + 0][r] = v.x; Kt[c0 + u + 1][r] = v.y;
                Kt[c0 + u + 2][r] = v.z; Kt[c0 + u + 3][r] = v.w;
            }
            #pragma unroll
            for (int u = 0; u < 16; u += 4)
                *(float4*)&Vs[r][c0 + u] = *(const float4*)&vp[u];
        }
        __syncthreads();

        float s[4][4];
        #pragma unroll
        for (int i = 0; i < 4; ++i) { s[i][0] = 0; s[i][1] = 0; s[i][2] = 0; s[i][3] = 0; }
        for (int dd = 0; dd < DHEAD; ++dd) {
            float a[4], kk4[4];
            *(float4*)a   = *(const float4*)&Qt[dd][tm * 4];
            *(float4*)kk4 = *(const float4*)&Kt[dd][tn * 4];
            #pragma unroll
            for (int i = 0; i < 4; ++i)
                #pragma unroll
                for (int j = 0; j < 4; ++j)
                    s[i][j] = fmaf(a[i], kk4[j], s[i][j]);
        }

        #pragma unroll
        for (int j = 0; j < 4; ++j) {
            if (j0 + tn * 4 + j >= SEQ) {
                #pragma unroll
                for (int i = 0; i < 4; ++i) s[i][j] = -1e30f;
            }
        }

        float p[4][4];
        #pragma unroll
        for (int i = 0; i < 4; ++i) {
            float tmax = fmaxf(fmaxf(s[i][0], s[i][1]), fmaxf(s[i][2], s[i][3]));
            tmax = fmaxf(tmax, __shfl_xor(tmax, 1));
            tmax = fmaxf(tmax, __shfl_xor(tmax, 2));
            tmax = fmaxf(tmax, __shfl_xor(tmax, 4));
            tmax = fmaxf(tmax, __shfl_xor(tmax, 8));
            float mnew = fmaxf(m_run[i], tmax);
            float f = __expf(m_run[i] - mnew);
            m_run[i] = mnew;
            float ps = 0.f;
            #pragma unroll
            for (int j = 0; j < 4; ++j) { p[i][j] = __expf(s[i][j] - mnew); ps += p[i][j]; }
            ps += __shfl_xor(ps, 1); ps += __shfl_xor(ps, 2);
            ps += __shfl_xor(ps, 4); ps += __shfl_xor(ps, 8);
            l_run[i] = l_run[i] * f + ps;
            #pragma unroll
            for (int j = 0; j < 4; ++j) acc[i][j] *= f;
        }

        #pragma unroll
        for (int i = 0; i < 4; ++i)
            #pragma unroll
            for (int j = 0; j < 4; ++j)
                Pt[tn * 4 + j][tm * 4 + i] = p[i][j];
        __syncthreads();

        for (int jj = 0; jj < 64; ++jj) {
            float pa[4], vv[4];
            *(float4*)pa = *(const float4*)&Pt[jj][tm * 4];
            *(float4*)vv = *(const float4*)&Vs[jj][tn * 4];
            #pragma unroll
            for (int i = 0; i < 4; ++i)
                #pragma unroll
                for (int c = 0; c < 4; ++c)
                    acc[i][c] = fmaf(pa[i], vv[c], acc[i][c]);
        }
    }

    #pragma unroll
    for (int i = 0; i < 4; ++i) {
        int n = q0 + tm * 4 + i;
        if (n < SEQ) {
            float inv = 1.0f / l_run[i];
            float4 o;
            o.x = acc[i][0] * inv; o.y = acc[i][1] * inv;
            o.z = acc[i][2] * inv; o.w = acc[i][3] * inv;
            // in-place: overwrite this token's q slice for this head
            *(float4*)&qkv[(size_t)(b * SEQ + n) * QKV_STRIDE + h * DHEAD + tn * 4] = o;
        }
    }
}

// ---------------- Row-0 attention probabilities (amap) — BEFORE attn ----------------
__global__ __launch_bounds__(256)
void row0_kernel(const float* __restrict__ qkv, float* __restrict__ amap)
{
    const int b = blockIdx.x / NHEADS, h = blockIdx.x % NHEADS;
    __shared__ float q0[DHEAD];
    __shared__ float sc[SEQ];
    __shared__ float red[256];
    const int tid = threadIdx.x;
    const float* qptr = qkv + (size_t)(b * SEQ) * QKV_STRIDE + h * DHEAD;
    if (tid < DHEAD) q0[tid] = qptr[tid] * 0.125f;
    __syncthreads();
    float lmax = -1e30f;
    for (int j = tid; j < SEQ; j += 256) {
        const float* kptr = qkv + (size_t)(b * SEQ + j) * QKV_STRIDE + CDIM + h * DHEAD;
        float s = 0.f;
        #pragma unroll
        for (int dd = 0; dd < DHEAD; dd += 4) {
            float4 kv = *(const float4*)&kptr[dd];
            s += q0[dd] * kv.x + q0[dd + 1] * kv.y + q0[dd + 2] * kv.z + q0[dd + 3] * kv.w;
        }
        sc[j] = s;
        lmax = fmaxf(lmax, s);
    }
    red[tid] = lmax; __syncthreads();
    for (int off = 128; off > 0; off >>= 1) {
        if (tid < off) red[tid] = fmaxf(red[tid], red[tid + off]);
        __syncthreads();
    }
    float mx = red[0]; __syncthreads();
    float lsum = 0.f;
    for (int j = tid; j < SEQ; j += 256) { float e = __expf(sc[j] - mx); sc[j] = e; lsum += e; }
    red[tid] = lsum; __syncthreads();
    for (int off = 128; off > 0; off >>= 1) {
        if (tid < off) red[tid] += red[tid + off];
        __syncthreads();
    }
    float inv = 1.0f / red[0];
    for (int j = tid; j < SEQ; j += 256)
        if (j >= 1) amap[(size_t)(b * NHEADS + h) * HWP + (j - 1)] = sc[j] * inv;
}

// ---------------- Structure branch (rank-1 collapsed) ----------------
__global__ __launch_bounds__(256)
void struct_kernel(const float* __restrict__ amap, const float* __restrict__ w_g1,
                   const float* __restrict__ w_g2, float* __restrict__ structv)
{
    const int b = blockIdx.x;
    __shared__ float ms[HWP];
    __shared__ float red[256];
    __shared__ int   redi[256];
    __shared__ float rt[GHID_];
    const int tid = threadIdx.x;

    float lsum = 0.f;
    for (int j = tid; j < HWP; j += 256) {
        float s = 0.f;
        #pragma unroll
        for (int h = 0; h < NHEADS; ++h) s += amap[(size_t)(b * NHEADS + h) * HWP + j];
        ms[j] = s; lsum += s;
    }
    red[tid] = lsum; __syncthreads();
    for (int off = 128; off > 0; off >>= 1) {
        if (tid < off) red[tid] += red[tid + off];
        __syncthreads();
    }
    const float thr = red[0] / (float)HWP;
    __syncthreads();

    float ls2 = 0.f; float lmax = -1.f; int lidx = HWP;
    for (int j = tid; j < HWP; j += 256) {
        float mv = (ms[j] > thr) ? ms[j] * (1.0f / NHEADS) : 0.0f;
        ms[j] = mv;
        ls2 += mv * mv;
        if (mv > lmax) { lmax = mv; lidx = j; }
    }
    red[tid] = lmax; redi[tid] = lidx; __syncthreads();
    for (int off = 128; off > 0; off >>= 1) {
        if (tid < off) {
            if (red[tid + off] > red[tid] ||
                (red[tid + off] == red[tid] && redi[tid + off] < redi[tid])) {
                red[tid] = red[tid + off]; redi[tid] = redi[tid + off];
            }
        }
        __syncthreads();
    }
    const int maxidx = redi[0];
    __syncthreads();
    red[tid] = ls2; __syncthreads();
    for (int off = 128; off > 0; off >>= 1) {
        if (tid < off) red[tid] += red[tid + off];
        __syncthreads();
    }
    const float s2 = red[0];
    __syncthreads();

    const int ai = maxidx / HGRID_, aj = maxidx % HGRID_;
    float ld0 = 0.f, ld1 = 0.f;
    for (int j = tid; j < HWP; j += 256) {
        float mv = ms[j];
        if (mv > 0.f) {
            float rx = (float)(j / HGRID_ - ai) * (1.0f / HGRID_);
            float ry = (float)(j % HGRID_ - aj) * (1.0f / HGRID_);
            float dist = sqrtf(rx * rx + ry * ry);
            float ang = atan2f(ry, rx) * 0.15915494309189535f + 0.5f;
            ld0 += mv * dist; ld1 += mv * ang;
        }
    }
    red[tid] = ld0; __syncthreads();
    for (int off = 128; off > 0; off >>= 1) {
        if (tid < off) red[tid] += red[tid + off];
        __syncthreads();
    }
    const float d0 = red[0]; __syncthreads();
    red[tid] = ld1; __syncthreads();
    for (int off = 128; off > 0; off >>= 1) {
        if (tid < off) red[tid] += red[tid + off];
        __syncthreads();
    }
    const float d1 = red[0]; __syncthreads();

    for (int hh = tid; hh < GHID_; hh += 256) {
        float t = d0 * w_g1[hh] + d1 * w_g1[GHID_ + hh];
        rt[hh] = fmaxf(t, 0.f);
    }
    __syncthreads();

    const float mi = ms[maxidx];
    for (int c = tid; c < CDIM; c += 256) {
        float g = 0.f;
        for (int hh = 0; hh < GHID_; ++hh)
            g = fmaf(rt[hh], w_g2[(size_t)hh * CDIM + c], g);
        float z = mi * s2 * g;
        structv[(size_t)b * CDIM + c] = (z > 0.f) ? z : 0.2f * z;
    }
}

extern "C" void kernel_launch(void* const* d_in, const int* in_sizes, int n_in,
                              void* d_out, int out_size, void* d_ws, size_t ws_size,
                              hipStream_t stream)
{
    const float* x      = (const float*)d_in[0];
    const float* w_qkv  = (const float*)d_in[1];
    const float* b_qkv  = (const float*)d_in[2];
    const float* w_proj = (const float*)d_in[3];
    const float* b_proj = (const float*)d_in[4];
    const float* w_g1   = (const float*)d_in[5];
    const float* w_g2   = (const float*)d_in[6];
    float* out = (float*)d_out;   // reference output dtype = float32

    // compact workspace: qkvbuf (y written in place over q-plane) + amap + structv
    const size_t need = ((size_t)NTOK * QKV_STRIDE
                         + (size_t)16 * NHEADS * HWP + (size_t)16 * CDIM) * 4; // 85.6 MB
    if (ws_size < need) {
        fill_sentinel_kernel<<<dim3((out_size + 255) / 256), dim3(256), 0, stream>>>(
            out, out_size);
        return;
    }

    float* ws      = (float*)d_ws;
    float* qkvbuf  = ws;                                    // 9232*2304 (q-plane becomes y)
    float* amap    = qkvbuf + (size_t)NTOK * QKV_STRIDE;    // 16*12*576
    float* structv = amap + (size_t)16 * NHEADS * HWP;      // 16*768

    dim3 blk(256);
    gemm_kernel<false><<<dim3(QKV_STRIDE / 128, (NTOK + 127) / 128), blk, 0, stream>>>(
        x, w_qkv, b_qkv, qkvbuf, nullptr, NTOK, QKV_STRIDE, CDIM, CDIM);
    // row0 needs pristine q row 0 -> must run BEFORE attn overwrites the q-plane
    row0_kernel<<<dim3(16 * NHEADS), blk, 0, stream>>>(qkvbuf, amap);
    attn_kernel<<<dim3(10, NHEADS, 16), blk, 0, stream>>>(qkvbuf);
    struct_kernel<<<dim3(16), blk, 0, stream>>>(amap, w_g1, w_g2, structv);
    // proj reads y from the q-plane (row stride QKV_STRIDE), writes fp32 out
    gemm_kernel<true><<<dim3(CDIM / 128, (NTOK + 127) / 128), blk, 0, stream>>>(
        qkvbuf, w_proj, b_proj, out, structv, NTOK, CDIM, CDIM, QKV_STRIDE);
}

// Round 13
// 694.231 us; speedup vs baseline: 1.5421x; 1.5421x over previous
//
#include <hip/hip_runtime.h>

#define SEQ 577
#define CDIM 768
#define NHEADS 12
#define DHEAD 64
#define QKV_STRIDE 2304
#define GHID_ 512
#define HGRID_ 24
#define HWP 576
#define NTOK 9232   // 16*577

typedef unsigned short u16;
typedef __bf16  bf16x8 __attribute__((ext_vector_type(8)));
typedef float   f32x4  __attribute__((ext_vector_type(4)));

__device__ __forceinline__ u16 f2bf(float x) {
    unsigned int u = __float_as_uint(x);
    unsigned int r = (u + 0x7FFFu + ((u >> 16) & 1u)) >> 16;
    return (u16)r;
}
__device__ __forceinline__ float bf2f(u16 b) {
    return __uint_as_float(((unsigned int)b) << 16);
}

// ---------------- sentinel fill (ws too small): out = 16.0f ----------------
__global__ __launch_bounds__(256)
void fill_sentinel_kernel(float* __restrict__ out, int n)
{
    int i = blockIdx.x * 256 + threadIdx.x;
    if (i < n) out[i] = 16.0f;
}

// ---------------- split + transpose: in[K][N] fp32 -> out[N][K] hi/lo bf16 ----------------
__global__ __launch_bounds__(256)
void split_transpose_kernel(const float* __restrict__ in, u16* __restrict__ oh,
                            u16* __restrict__ ol, int K, int N)
{
    __shared__ float t[32][33];
    const int n0 = blockIdx.x * 32, k0 = blockIdx.y * 32;
    const int r = threadIdx.x >> 3;
    const int c = (threadIdx.x & 7) << 2;
    float4 v = *(const float4*)&in[(size_t)(k0 + r) * N + n0 + c];
    t[r][c] = v.x; t[r][c + 1] = v.y; t[r][c + 2] = v.z; t[r][c + 3] = v.w;
    __syncthreads();
    float f[4] = {t[c + 0][r], t[c + 1][r], t[c + 2][r], t[c + 3][r]};
    u16 hv[4], lv[4];
    #pragma unroll
    for (int j = 0; j < 4; ++j) {
        hv[j] = f2bf(f[j]);
        lv[j] = f2bf(f[j] - bf2f(hv[j]));
    }
    size_t o = (size_t)(n0 + r) * K + k0 + c;
    *(ushort4*)&oh[o] = *(ushort4*)&hv[0];
    *(ushort4*)&ol[o] = *(ushort4*)&lv[0];
}

// ---------------- split-bf16 MFMA GEMM ----------------
// C(M,N) = A(M,K) @ B + bias, B given pre-split transposed: Bh/Bl [N][K] bf16.
// A: if ASPLIT, Ah/Al [M][lda] bf16 pair; else Af [M][lda] fp32 (split on the fly).
// Output: if PROJ, fp32 C (+structv on token-0 rows); else hi/lo bf16 pair Ch/Cl.
// 128x128 tile, BK=32, 4 waves (2x2), each wave 64x64 via 4x4 frags of 16x16x32.
// Split product: C = Ah*Bh + Ah*Bl + Al*Bh  (Al*Bl ~ 2^-16, dropped).
template<bool ASPLIT, bool PROJ>
__global__ __launch_bounds__(256)
void mfma_gemm_kernel(const float* __restrict__ Af,
                      const u16* __restrict__ Ah, const u16* __restrict__ Al,
                      const u16* __restrict__ Bh, const u16* __restrict__ Bl,
                      const float* __restrict__ bias,
                      float* __restrict__ Cf, u16* __restrict__ Ch, u16* __restrict__ Cl,
                      const float* __restrict__ structv,
                      int M, int N, int K, int lda)
{
    // 80-byte (40-short) row stride LDS tiles
    __shared__ __align__(16) u16 As_h[128 * 40];
    __shared__ __align__(16) u16 As_l[128 * 40];
    __shared__ __align__(16) u16 Bs_h[128 * 40];
    __shared__ __align__(16) u16 Bs_l[128 * 40];

    const int tid = threadIdx.x;
    const int m0 = blockIdx.y * 128;
    const int n0 = blockIdx.x * 128;

    f32x4 acc[4][4];
    #pragma unroll
    for (int i = 0; i < 4; ++i)
        #pragma unroll
        for (int j = 0; j < 4; ++j) acc[i][j] = (f32x4){0.f, 0.f, 0.f, 0.f};

    // staging: thread -> (row sr, 16-elem chunk sc)
    const int sr = tid >> 1;
    const int sc = (tid & 1) << 4;
    int ga = m0 + sr; if (ga >= M) ga = M - 1;   // clamp; extra rows never stored
    const int lw = sr * 40 + sc;

    // fragment addressing
    const int lane = tid & 63;
    const int wm = ((tid >> 7) & 1) * 64;   // wave row offset (2x2 wave grid)
    const int wn = ((tid >> 6) & 1) * 64;   // wave col offset
    const int fr = lane & 15;
    const int fgo = (lane >> 4) * 8;        // k-element offset within 32

    for (int k0 = 0; k0 < K; k0 += 32) {
        // ---- stage A ----
        if (ASPLIT) {
            const u16* pAh = Ah + (size_t)ga * lda + k0 + sc;
            const u16* pAl = Al + (size_t)ga * lda + k0 + sc;
            *(int4*)&As_h[lw]     = *(const int4*)(pAh);
            *(int4*)&As_h[lw + 8] = *(const int4*)(pAh + 8);
            *(int4*)&As_l[lw]     = *(const int4*)(pAl);
            *(int4*)&As_l[lw + 8] = *(const int4*)(pAl + 8);
        } else {
            const float* pA = Af + (size_t)ga * lda + k0 + sc;
            u16 hbuf[16], lbuf[16];
            #pragma unroll
            for (int u = 0; u < 16; u += 4) {
                float4 v = *(const float4*)&pA[u];
                float f[4] = {v.x, v.y, v.z, v.w};
                #pragma unroll
                for (int j = 0; j < 4; ++j) {
                    u16 h = f2bf(f[j]);
                    hbuf[u + j] = h;
                    lbuf[u + j] = f2bf(f[j] - bf2f(h));
                }
            }
            *(int4*)&As_h[lw]     = *(int4*)&hbuf[0];
            *(int4*)&As_h[lw + 8] = *(int4*)&hbuf[8];
            *(int4*)&As_l[lw]     = *(int4*)&lbuf[0];
            *(int4*)&As_l[lw + 8] = *(int4*)&lbuf[8];
        }
        // ---- stage B (pre-split B^T [N][K]) ----
        {
            const u16* pBh = Bh + (size_t)(n0 + sr) * K + k0 + sc;
            const u16* pBl = Bl + (size_t)(n0 + sr) * K + k0 + sc;
            *(int4*)&Bs_h[lw]     = *(const int4*)(pBh);
            *(int4*)&Bs_h[lw + 8] = *(const int4*)(pBh + 8);
            *(int4*)&Bs_l[lw]     = *(const int4*)(pBl);
            *(int4*)&Bs_l[lw + 8] = *(const int4*)(pBl + 8);
        }
        __syncthreads();

        bf16x8 ah[4], al[4], bh[4], bl[4];
        #pragma unroll
        for (int i = 0; i < 4; ++i) {
            const int ab = (wm + i * 16 + fr) * 40 + fgo;
            ah[i] = __builtin_bit_cast(bf16x8, *(const int4*)&As_h[ab]);
            al[i] = __builtin_bit_cast(bf16x8, *(const int4*)&As_l[ab]);
            const int bb = (wn + i * 16 + fr) * 40 + fgo;
            bh[i] = __builtin_bit_cast(bf16x8, *(const int4*)&Bs_h[bb]);
            bl[i] = __builtin_bit_cast(bf16x8, *(const int4*)&Bs_l[bb]);
        }

        #pragma unroll
        for (int mi = 0; mi < 4; ++mi)
            #pragma unroll
            for (int ni = 0; ni < 4; ++ni) {
                acc[mi][ni] = __builtin_amdgcn_mfma_f32_16x16x32_bf16(ah[mi], bh[ni], acc[mi][ni], 0, 0, 0);
                acc[mi][ni] = __builtin_amdgcn_mfma_f32_16x16x32_bf16(ah[mi], bl[ni], acc[mi][ni], 0, 0, 0);
                acc[mi][ni] = __builtin_amdgcn_mfma_f32_16x16x32_bf16(al[mi], bh[ni], acc[mi][ni], 0, 0, 0);
            }
        __syncthreads();
    }

    // epilogue: C/D layout col = lane&15, row = 4*(lane>>4) + reg  [m89-verified]
    #pragma unroll
    for (int mi = 0; mi < 4; ++mi) {
        const int rbase = m0 + wm + mi * 16 + (lane >> 4) * 4;
        #pragma unroll
        for (int ni = 0; ni < 4; ++ni) {
            const int col = n0 + wn + ni * 16 + fr;
            const float bv = bias[col];
            #pragma unroll
            for (int j = 0; j < 4; ++j) {
                const int row = rbase + j;
                if (row < M) {
                    float v = acc[mi][ni][j] + bv;
                    if (PROJ) {
                        if (row % SEQ == 0) v += structv[(size_t)(row / SEQ) * CDIM + col];
                        Cf[(size_t)row * N + col] = v;
                    } else {
                        u16 hh = f2bf(v);
                        Ch[(size_t)row * N + col] = hh;
                        Cl[(size_t)row * N + col] = f2bf(v - bf2f(hh));
                    }
                }
            }
        }
    }
}

// ---------------- Flash attention (fp32 from split qkv); y in place over q-plane ----------------
// Safe: each block reads its Q into LDS in the prologue, heads write disjoint
// 64-col slices, K/V planes never written. row0 runs BEFORE this kernel.
__global__ __launch_bounds__(256)
void attn_kernel(u16* qkvh, u16* qkvl)
{
    __shared__ float Qt[DHEAD][68];   // Q transposed [d][m], pre-scaled
    __shared__ float Kt[DHEAD][68];   // K transposed [d][j]
    __shared__ float Vs[64][68];      // V row-major [j][d]
    __shared__ float Pt[64][68];      // P transposed [j][m]
    const int tid = threadIdx.x;
    const int tm = tid >> 4, tn = tid & 15;
    const int qt = blockIdx.x, h = blockIdx.y, b = blockIdx.z;
    const int q0 = qt * 64;

    {
        int r = tid >> 2;
        int c0 = (tid & 3) << 4;
        int n = q0 + r; if (n > SEQ - 1) n = SEQ - 1;
        size_t base = (size_t)(b * SEQ + n) * QKV_STRIDE + h * DHEAD + c0;
        u16 hs[16], ls[16];
        *(int4*)&hs[0] = *(const int4*)&qkvh[base];
        *(int4*)&hs[8] = *(const int4*)&qkvh[base + 8];
        *(int4*)&ls[0] = *(const int4*)&qkvl[base];
        *(int4*)&ls[8] = *(const int4*)&qkvl[base + 8];
        #pragma unroll
        for (int u = 0; u < 16; ++u)
            Qt[c0 + u][r] = (bf2f(hs[u]) + bf2f(ls[u])) * 0.125f;
    }

    float m_run[4], l_run[4], acc[4][4];
    #pragma unroll
    for (int i = 0; i < 4; ++i) {
        m_run[i] = -1e30f; l_run[i] = 0.f;
        #pragma unroll
        for (int j = 0; j < 4; ++j) acc[i][j] = 0.f;
    }

    for (int kt = 0; kt < 10; ++kt) {
        const int j0 = kt * 64;
        __syncthreads();   // previous PV done (and Q visible on first iter)
        {
            int r = tid >> 2;
            int c0 = (tid & 3) << 4;
            int n = j0 + r; if (n > SEQ - 1) n = SEQ - 1;
            size_t kb = (size_t)(b * SEQ + n) * QKV_STRIDE + CDIM + h * DHEAD + c0;
            size_t vb = kb + CDIM;
            u16 hs[16], ls[16];
            *(int4*)&hs[0] = *(const int4*)&qkvh[kb];
            *(int4*)&hs[8] = *(const int4*)&qkvh[kb + 8];
            *(int4*)&ls[0] = *(const int4*)&qkvl[kb];
            *(int4*)&ls[8] = *(const int4*)&qkvl[kb + 8];
            #pragma unroll
            for (int u = 0; u < 16; ++u)
                Kt[c0 + u][r] = bf2f(hs[u]) + bf2f(ls[u]);
            *(int4*)&hs[0] = *(const int4*)&qkvh[vb];
            *(int4*)&hs[8] = *(const int4*)&qkvh[vb + 8];
            *(int4*)&ls[0] = *(const int4*)&qkvl[vb];
            *(int4*)&ls[8] = *(const int4*)&qkvl[vb + 8];
            #pragma unroll
            for (int u = 0; u < 16; ++u)
                Vs[r][c0 + u] = bf2f(hs[u]) + bf2f(ls[u]);
        }
        __syncthreads();

        float s[4][4];
        #pragma unroll
        for (int i = 0; i < 4; ++i) { s[i][0] = 0; s[i][1] = 0; s[i][2] = 0; s[i][3] = 0; }
        for (int dd = 0; dd < DHEAD; ++dd) {
            float a[4], kk4[4];
            *(float4*)a   = *(const float4*)&Qt[dd][tm * 4];
            *(float4*)kk4 = *(const float4*)&Kt[dd][tn * 4];
            #pragma unroll
            for (int i = 0; i < 4; ++i)
                #pragma unroll
                for (int j = 0; j < 4; ++j)
                    s[i][j] = fmaf(a[i], kk4[j], s[i][j]);
        }

        #pragma unroll
        for (int j = 0; j < 4; ++j) {
            if (j0 + tn * 4 + j >= SEQ) {
                #pragma unroll
                for (int i = 0; i < 4; ++i) s[i][j] = -1e30f;
            }
        }

        float p[4][4];
        #pragma unroll
        for (int i = 0; i < 4; ++i) {
            float tmax = fmaxf(fmaxf(s[i][0], s[i][1]), fmaxf(s[i][2], s[i][3]));
            tmax = fmaxf(tmax, __shfl_xor(tmax, 1));
            tmax = fmaxf(tmax, __shfl_xor(tmax, 2));
            tmax = fmaxf(tmax, __shfl_xor(tmax, 4));
            tmax = fmaxf(tmax, __shfl_xor(tmax, 8));
            float mnew = fmaxf(m_run[i], tmax);
            float f = __expf(m_run[i] - mnew);
            m_run[i] = mnew;
            float ps = 0.f;
            #pragma unroll
            for (int j = 0; j < 4; ++j) { p[i][j] = __expf(s[i][j] - mnew); ps += p[i][j]; }
            ps += __shfl_xor(ps, 1); ps += __shfl_xor(ps, 2);
            ps += __shfl_xor(ps, 4); ps += __shfl_xor(ps, 8);
            l_run[i] = l_run[i] * f + ps;
            #pragma unroll
            for (int j = 0; j < 4; ++j) acc[i][j] *= f;
        }

        #pragma unroll
        for (int i = 0; i < 4; ++i)
            #pragma unroll
            for (int j = 0; j < 4; ++j)
                Pt[tn * 4 + j][tm * 4 + i] = p[i][j];
        __syncthreads();

        for (int jj = 0; jj < 64; ++jj) {
            float pa[4], vv[4];
            *(float4*)pa = *(const float4*)&Pt[jj][tm * 4];
            *(float4*)vv = *(const float4*)&Vs[jj][tn * 4];
            #pragma unroll
            for (int i = 0; i < 4; ++i)
                #pragma unroll
                for (int c = 0; c < 4; ++c)
                    acc[i][c] = fmaf(pa[i], vv[c], acc[i][c]);
        }
    }

    #pragma unroll
    for (int i = 0; i < 4; ++i) {
        int n = q0 + tm * 4 + i;
        if (n < SEQ) {
            float inv = 1.0f / l_run[i];
            size_t off = (size_t)(b * SEQ + n) * QKV_STRIDE + h * DHEAD + tn * 4;
            #pragma unroll
            for (int c = 0; c < 4; ++c) {
                float v = acc[i][c] * inv;
                u16 hh = f2bf(v);
                qkvh[off + c] = hh;
                qkvl[off + c] = f2bf(v - bf2f(hh));
            }
        }
    }
}

// ---------------- Row-0 attention probabilities (amap) — BEFORE attn ----------------
__global__ __launch_bounds__(256)
void row0_kernel(const u16* __restrict__ qkvh, const u16* __restrict__ qkvl,
                 float* __restrict__ amap)
{
    const int b = blockIdx.x / NHEADS, h = blockIdx.x % NHEADS;
    __shared__ float q0s[DHEAD];
    __shared__ float sc[SEQ];
    __shared__ float red[256];
    const int tid = threadIdx.x;
    const size_t qb = (size_t)(b * SEQ) * QKV_STRIDE + h * DHEAD;
    if (tid < DHEAD) q0s[tid] = (bf2f(qkvh[qb + tid]) + bf2f(qkvl[qb + tid])) * 0.125f;
    __syncthreads();
    float lmax = -1e30f;
    for (int j = tid; j < SEQ; j += 256) {
        const size_t kb = (size_t)(b * SEQ + j) * QKV_STRIDE + CDIM + h * DHEAD;
        float s = 0.f;
        #pragma unroll
        for (int dd = 0; dd < DHEAD; dd += 8) {
            u16 hs[8], ls[8];
            *(int4*)&hs[0] = *(const int4*)&qkvh[kb + dd];
            *(int4*)&ls[0] = *(const int4*)&qkvl[kb + dd];
            #pragma unroll
            for (int u = 0; u < 8; ++u)
                s = fmaf(q0s[dd + u], bf2f(hs[u]) + bf2f(ls[u]), s);
        }
        sc[j] = s;
        lmax = fmaxf(lmax, s);
    }
    red[tid] = lmax; __syncthreads();
    for (int off = 128; off > 0; off >>= 1) {
        if (tid < off) red[tid] = fmaxf(red[tid], red[tid + off]);
        __syncthreads();
    }
    float mx = red[0]; __syncthreads();
    float lsum = 0.f;
    for (int j = tid; j < SEQ; j += 256) { float e = __expf(sc[j] - mx); sc[j] = e; lsum += e; }
    red[tid] = lsum; __syncthreads();
    for (int off = 128; off > 0; off >>= 1) {
        if (tid < off) red[tid] += red[tid + off];
        __syncthreads();
    }
    float inv = 1.0f / red[0];
    for (int j = tid; j < SEQ; j += 256)
        if (j >= 1) amap[(size_t)(b * NHEADS + h) * HWP + (j - 1)] = sc[j] * inv;
}

// ---------------- Structure branch (rank-1 collapsed) ----------------
__global__ __launch_bounds__(256)
void struct_kernel(const float* __restrict__ amap, const float* __restrict__ w_g1,
                   const float* __restrict__ w_g2, float* __restrict__ structv)
{
    const int b = blockIdx.x;
    __shared__ float ms[HWP];
    __shared__ float red[256];
    __shared__ int   redi[256];
    __shared__ float rt[GHID_];
    const int tid = threadIdx.x;

    float lsum = 0.f;
    for (int j = tid; j < HWP; j += 256) {
        float s = 0.f;
        #pragma unroll
        for (int h = 0; h < NHEADS; ++h) s += amap[(size_t)(b * NHEADS + h) * HWP + j];
        ms[j] = s; lsum += s;
    }
    red[tid] = lsum; __syncthreads();
    for (int off = 128; off > 0; off >>= 1) {
        if (tid < off) red[tid] += red[tid + off];
        __syncthreads();
    }
    const float thr = red[0] / (float)HWP;
    __syncthreads();

    float ls2 = 0.f; float lmax = -1.f; int lidx = HWP;
    for (int j = tid; j < HWP; j += 256) {
        float mv = (ms[j] > thr) ? ms[j] * (1.0f / NHEADS) : 0.0f;
        ms[j] = mv;
        ls2 += mv * mv;
        if (mv > lmax) { lmax = mv; lidx = j; }
    }
    red[tid] = lmax; redi[tid] = lidx; __syncthreads();
    for (int off = 128; off > 0; off >>= 1) {
        if (tid < off) {
            if (red[tid + off] > red[tid] ||
                (red[tid + off] == red[tid] && redi[tid + off] < redi[tid])) {
                red[tid] = red[tid + off]; redi[tid] = redi[tid + off];
            }
        }
        __syncthreads();
    }
    const int maxidx = redi[0];
    __syncthreads();
    red[tid] = ls2; __syncthreads();
    for (int off = 128; off > 0; off >>= 1) {
        if (tid < off) red[tid] += red[tid + off];
        __syncthreads();
    }
    const float s2 = red[0];
    __syncthreads();

    const int ai = maxidx / HGRID_, aj = maxidx % HGRID_;
    float ld0 = 0.f, ld1 = 0.f;
    for (int j = tid; j < HWP; j += 256) {
        float mv = ms[j];
        if (mv > 0.f) {
            float rx = (float)(j / HGRID_ - ai) * (1.0f / HGRID_);
            float ry = (float)(j % HGRID_ - aj) * (1.0f / HGRID_);
            float dist = sqrtf(rx * rx + ry * ry);
            float ang = atan2f(ry, rx) * 0.15915494309189535f + 0.5f;
            ld0 += mv * dist; ld1 += mv * ang;
        }
    }
    red[tid] = ld0; __syncthreads();
    for (int off = 128; off > 0; off >>= 1) {
        if (tid < off) red[tid] += red[tid + off];
        __syncthreads();
    }
    const float d0 = red[0]; __syncthreads();
    red[tid] = ld1; __syncthreads();
    for (int off = 128; off > 0; off >>= 1) {
        if (tid < off) red[tid] += red[tid + off];
        __syncthreads();
    }
    const float d1 = red[0]; __syncthreads();

    for (int hh = tid; hh < GHID_; hh += 256) {
        float t = d0 * w_g1[hh] + d1 * w_g1[GHID_ + hh];
        rt[hh] = fmaxf(t, 0.f);
    }
    __syncthreads();

    const float mi = ms[maxidx];
    for (int c = tid; c < CDIM; c += 256) {
        float g = 0.f;
        for (int hh = 0; hh < GHID_; ++hh)
            g = fmaf(rt[hh], w_g2[(size_t)hh * CDIM + c], g);
        float z = mi * s2 * g;
        structv[(size_t)b * CDIM + c] = (z > 0.f) ? z : 0.2f * z;
    }
}

extern "C" void kernel_launch(void* const* d_in, const int* in_sizes, int n_in,
                              void* d_out, int out_size, void* d_ws, size_t ws_size,
                              hipStream_t stream)
{
    const float* x      = (const float*)d_in[0];
    const float* w_qkv  = (const float*)d_in[1];
    const float* b_qkv  = (const float*)d_in[2];
    const float* w_proj = (const float*)d_in[3];
    const float* b_proj = (const float*)d_in[4];
    const float* w_g1   = (const float*)d_in[5];
    const float* w_g2   = (const float*)d_in[6];
    float* out = (float*)d_out;   // reference output dtype = float32

    // workspace: qkv hi/lo split (q-plane becomes y) + weight splits + amap + structv
    // = 85,082,112 + 7,077,888 + 2,359,296 + 442,368 + 49,152 = 95,010,816 B
    const size_t need = (size_t)NTOK * QKV_STRIDE * 4      // qkvh+qkvl
                      + (size_t)QKV_STRIDE * CDIM * 4      // wqth+wqtl
                      + (size_t)CDIM * CDIM * 4            // wpth+wptl
                      + (size_t)16 * NHEADS * HWP * 4
                      + (size_t)16 * CDIM * 4;
    if (ws_size < need) {
        fill_sentinel_kernel<<<dim3((out_size + 255) / 256), dim3(256), 0, stream>>>(
            out, out_size);
        return;
    }

    char* w = (char*)d_ws;
    u16* qkvh = (u16*)w;  w += (size_t)NTOK * QKV_STRIDE * 2;
    u16* qkvl = (u16*)w;  w += (size_t)NTOK * QKV_STRIDE * 2;
    u16* wqth = (u16*)w;  w += (size_t)QKV_STRIDE * CDIM * 2;
    u16* wqtl = (u16*)w;  w += (size_t)QKV_STRIDE * CDIM * 2;
    u16* wpth = (u16*)w;  w += (size_t)CDIM * CDIM * 2;
    u16* wptl = (u16*)w;  w += (size_t)CDIM * CDIM * 2;
    float* amap    = (float*)w;  w += (size_t)16 * NHEADS * HWP * 4;
    float* structv = (float*)w;

    dim3 blk(256);
    // weight splits (transposed to [N][K])
    split_transpose_kernel<<<dim3(QKV_STRIDE / 32, CDIM / 32), blk, 0, stream>>>(
        w_qkv, wqth, wqtl, CDIM, QKV_STRIDE);
    split_transpose_kernel<<<dim3(CDIM / 32, CDIM / 32), blk, 0, stream>>>(
        w_proj, wpth, wptl, CDIM, CDIM);
    // qkv = x @ w_qkv + b  (A split on the fly; output stored as hi/lo pair)
    mfma_gemm_kernel<false, false><<<dim3(QKV_STRIDE / 128, (NTOK + 127) / 128), blk, 0, stream>>>(
        x, nullptr, nullptr, wqth, wqtl, b_qkv, nullptr, qkvh, qkvl, nullptr,
        NTOK, QKV_STRIDE, CDIM, CDIM);
    // row0 needs pristine q row 0 -> BEFORE attn overwrites the q-plane
    row0_kernel<<<dim3(16 * NHEADS), blk, 0, stream>>>(qkvh, qkvl, amap);
    attn_kernel<<<dim3(10, NHEADS, 16), blk, 0, stream>>>(qkvh, qkvl);
    struct_kernel<<<dim3(16), blk, 0, stream>>>(amap, w_g1, w_g2, structv);
    // out = y @ w_proj + b (+ structure on token 0); A = y split pair, fp32 out
    mfma_gemm_kernel<true, true><<<dim3(CDIM / 128, (NTOK + 127) / 128), blk, 0, stream>>>(
        nullptr, qkvh, qkvl, wpth, wptl, b_proj, out, nullptr, nullptr, structv,
        NTOK, CDIM, CDIM, QKV_STRIDE);
}